// Round 2
// baseline (1389.063 us; speedup 1.0000x reference)
//
#include <hip/hip_runtime.h>
#include <stdint.h>

typedef __attribute__((ext_vector_type(4))) float f32x4;
typedef __attribute__((ext_vector_type(8))) _Float16 f16x8;

#define L_BATCH 1024
#define L_HID   512
#define L_LAT   256

static __device__ __forceinline__ unsigned short f2h(float f) {
    union { _Float16 h; unsigned short u; } v;
    v.h = (_Float16)f;                      // v_cvt_f16_f32, RNE
    return v.u;
}
static __device__ __forceinline__ f16x8 as_f16x8(uint4 v) {
    union { uint4 u; f16x8 s; } x; x.u = v; return x.s;
}
static __device__ __forceinline__ float sigmoid_fast(float x) {
    return __builtin_amdgcn_rcpf(1.0f + __builtin_amdgcn_exp2f(-1.4426950408889634f * x));
}
static __device__ __forceinline__ float tanh_fast(float x) {
    return 1.0f - 2.0f * __builtin_amdgcn_rcpf(1.0f + __builtin_amdgcn_exp2f(2.8853900817779268f * x));
}

// ---------- fp32 -> fp16 with dst row stride (handles concat into hc) ----------
__global__ void convert_strided(const float* __restrict__ src, unsigned short* __restrict__ dst,
                                int rows, int cols, int dst_stride) {
    int i = blockIdx.x * blockDim.x + threadIdx.x;
    int base = i * 4;
    if (base >= rows * cols) return;
    int r = base / cols, c = base % cols;      // cols multiple of 4
    float4 v = *(const float4*)(src + base);
    unsigned short* d = dst + (size_t)r * dst_stride + c;
    d[0] = f2h(v.x); d[1] = f2h(v.y); d[2] = f2h(v.z); d[3] = f2h(v.w);
}

// ---------- generic C[M,N] = A[M,lda(fp16)] @ W[N,K(fp16)]^T + bias (+ELU) ----------
__global__ __launch_bounds__(256) void gemm_bt(
    const unsigned short* __restrict__ A, const unsigned short* __restrict__ W,
    float* __restrict__ C, const float* __restrict__ b1, const float* __restrict__ b2,
    int K, int lda, int N, int do_elu) {
    __shared__ unsigned short As[64][40];   // pad to 80B rows (bank-friendly)
    __shared__ unsigned short Bs[64][40];
    int tid = threadIdx.x;
    int lane = tid & 63, wv = tid >> 6;
    int q = lane >> 4, l15 = lane & 15;
    int Mbase = blockIdx.x * 64, Nbase = blockIdx.y * 64;
    int ldrow = tid >> 2, seg = tid & 3;
    const unsigned short* Ap = A + (size_t)(Mbase + ldrow) * lda + seg * 8;
    const unsigned short* Wp = W + (size_t)(Nbase + ldrow) * K + seg * 8;
    f32x4 acc[4] = {};
    for (int k0 = 0; k0 < K; k0 += 32) {
        uint4 av = *(const uint4*)(Ap + k0);
        uint4 wvv = *(const uint4*)(Wp + k0);
        __syncthreads();
        *(uint4*)(&As[ldrow][seg * 8]) = av;
        *(uint4*)(&Bs[ldrow][seg * 8]) = wvv;
        __syncthreads();
        f16x8 af = *(const f16x8*)(&As[wv * 16 + l15][q * 8]);
#pragma unroll
        for (int nt = 0; nt < 4; nt++) {
            f16x8 bf = *(const f16x8*)(&Bs[nt * 16 + l15][q * 8]);
            acc[nt] = __builtin_amdgcn_mfma_f32_16x16x32_f16(af, bf, acc[nt], 0, 0, 0);
        }
    }
#pragma unroll
    for (int nt = 0; nt < 4; nt++) {
        int col = Nbase + nt * 16 + l15;
        float bias = b1[col] + (b2 ? b2[col] : 0.0f);
#pragma unroll
        for (int r = 0; r < 4; r++) {
            int row = Mbase + wv * 16 + q * 4 + r;
            float v = acc[nt][r] + bias;
            if (do_elu) v = v > 0.0f ? v : (__builtin_amdgcn_exp2f(1.4426950408889634f * v) - 1.0f);
            C[(size_t)row * N + col] = v;
        }
    }
}

// ---------- persistent recurrent kernel: 64 blocks x 1024 thr, 16 rows/block ----------
// wave w owns latent cols [16w,16w+16) for all 4 gates (i,f,g,o in-register elementwise).
// W_hh frags: kt0-1 in VGPRs, kt2-3 in LDS, kt4-7 streamed from L2 each step (prefetched).
#define HB_STRIDE 264                    // fp16 elems per h row (padded)
#define HB_HALF   (16 * HB_STRIDE)      // one h buffer, elems
#define WLDS_OFF  (2 * HB_HALF * 2)     // bytes: 16896
#define LSTM_LDS_BYTES (WLDS_OFF + 16 * 8 * 64 * 16)   // 147968

__global__ __launch_bounds__(1024) void lstm_rec(
    const unsigned short* __restrict__ Whh,   // [1024,256] fp16
    const float* __restrict__ xp,             // [1024,1024]
    const float* __restrict__ h0,             // [1024,256]
    const float* __restrict__ c0,             // [1024,256]
    const int* __restrict__ seq_len,
    float* __restrict__ out)                  // [1024, T, 256]
{
    extern __shared__ unsigned char smem[];
    unsigned short* hbuf = (unsigned short*)smem;        // [2][16][HB_STRIDE]
    unsigned char* wlds = smem + WLDS_OFF;               // 16 waves * 8 frags * 64 lanes * 16B
    int tid = threadIdx.x;
    int lane = tid & 63, wv = tid >> 6;
    int q = lane >> 4, l15 = lane & 15;
    int T = *seq_len;
    int rowbase = blockIdx.x * 16;

    // global base for this wave's weight fragments: row = g*256 + wv*16 + l15, k = kt*32 + q*8
    const unsigned short* wbase = Whh + ((wv << 4) + l15) * 256 + q * 8;

    uint4 wreg[8];
#pragma unroll
    for (int kt = 0; kt < 2; kt++)
#pragma unroll
        for (int g = 0; g < 4; g++)
            wreg[kt * 4 + g] = *(const uint4*)(wbase + (size_t)g * 65536 + kt * 32);
#pragma unroll
    for (int kt = 2; kt < 4; kt++)
#pragma unroll
        for (int g = 0; g < 4; g++) {
            uint4 v = *(const uint4*)(wbase + (size_t)g * 65536 + kt * 32);
            *(uint4*)(wlds + ((size_t)((wv * 8) + (kt - 2) * 4 + g) * 64 + lane) * 16) = v;
        }

    float xpr[16];
#pragma unroll
    for (int g = 0; g < 4; g++)
#pragma unroll
        for (int r = 0; r < 4; r++)
            xpr[g * 4 + r] = xp[(size_t)(rowbase + q * 4 + r) * 1024 + g * 256 + wv * 16 + l15];

    float creg[4];
#pragma unroll
    for (int r = 0; r < 4; r++)
        creg[r] = c0[(size_t)(rowbase + q * 4 + r) * 256 + wv * 16 + l15];

    {   // h0 -> hbuf[0] as fp16
        int e = tid * 4;
        int r = e >> 8, cc = e & 255;
        float4 v = *(const float4*)(h0 + (size_t)(rowbase + r) * 256 + cc);
        unsigned short* d = hbuf + r * HB_STRIDE + cc;
        d[0] = f2h(v.x); d[1] = f2h(v.y); d[2] = f2h(v.z); d[3] = f2h(v.w);
    }
    __syncthreads();

    // prefetch streamed kt4 (weight addresses are step-invariant)
    uint4 sbuf[4];
#pragma unroll
    for (int g = 0; g < 4; g++) sbuf[g] = *(const uint4*)(wbase + (size_t)g * 65536 + 4 * 32);

    for (int t = 0; t < T; t++) {
        unsigned short* hc = hbuf + (t & 1) * HB_HALF;
        f32x4 acc[4];
#pragma unroll
        for (int g = 0; g < 4; g++) {
            acc[g][0] = xpr[g * 4 + 0]; acc[g][1] = xpr[g * 4 + 1];
            acc[g][2] = xpr[g * 4 + 2]; acc[g][3] = xpr[g * 4 + 3];
        }
        // kt 0..1: register-resident weights
#pragma unroll
        for (int kt = 0; kt < 2; kt++) {
            f16x8 af = *(const f16x8*)(hc + l15 * HB_STRIDE + kt * 32 + q * 8);
#pragma unroll
            for (int g = 0; g < 4; g++)
                acc[g] = __builtin_amdgcn_mfma_f32_16x16x32_f16(af, as_f16x8(wreg[kt * 4 + g]), acc[g], 0, 0, 0);
        }
        // kt 2..3: LDS-resident weights
#pragma unroll
        for (int kt = 2; kt < 4; kt++) {
            f16x8 af = *(const f16x8*)(hc + l15 * HB_STRIDE + kt * 32 + q * 8);
#pragma unroll
            for (int g = 0; g < 4; g++) {
                f16x8 bf = *(const f16x8*)(wlds + ((size_t)((wv * 8) + (kt - 2) * 4 + g) * 64 + lane) * 16);
                acc[g] = __builtin_amdgcn_mfma_f32_16x16x32_f16(af, bf, acc[g], 0, 0, 0);
            }
        }
        // kt 4..7: streamed from L2, prefetched one k-tile ahead (kt7 prefetches next step's kt4)
#pragma unroll
        for (int kt = 4; kt < 8; kt++) {
            f16x8 af = *(const f16x8*)(hc + l15 * HB_STRIDE + kt * 32 + q * 8);
            uint4 cur4[4];
#pragma unroll
            for (int g = 0; g < 4; g++) cur4[g] = sbuf[g];
            int nkt = (kt < 7) ? (kt + 1) : 4;
#pragma unroll
            for (int g = 0; g < 4; g++) sbuf[g] = *(const uint4*)(wbase + (size_t)g * 65536 + nkt * 32);
#pragma unroll
            for (int g = 0; g < 4; g++)
                acc[g] = __builtin_amdgcn_mfma_f32_16x16x32_f16(af, as_f16x8(cur4[g]), acc[g], 0, 0, 0);
        }
        // elementwise (in-register), write ys and next h
        unsigned short* hn = hbuf + ((t + 1) & 1) * HB_HALF;
#pragma unroll
        for (int r = 0; r < 4; r++) {
            float ig = sigmoid_fast(acc[0][r]);
            float fg = sigmoid_fast(acc[1][r]);
            float gg = tanh_fast(acc[2][r]);
            float og = sigmoid_fast(acc[3][r]);
            float cn = fg * creg[r] + ig * gg;
            creg[r] = cn;
            float hv = og * tanh_fast(cn);
            out[((size_t)(rowbase + q * 4 + r) * T + t) * 256 + wv * 16 + l15] = hv;
            hn[(q * 4 + r) * HB_STRIDE + wv * 16 + l15] = f2h(hv);
        }
        __syncthreads();
    }
}

extern "C" void kernel_launch(void* const* d_in, const int* in_sizes, int n_in,
                              void* d_out, int out_size, void* d_ws, size_t ws_size,
                              hipStream_t stream) {
    const float* h   = (const float*)d_in[0];
    const float* c   = (const float*)d_in[1];
    const int*   seqp= (const int*)d_in[2];
    const float* iWh = (const float*)d_in[3];
    const float* ibh = (const float*)d_in[4];
    const float* iWc = (const float*)d_in[5];
    const float* ibc = (const float*)d_in[6];
    const float* Wih = (const float*)d_in[7];
    const float* Whh = (const float*)d_in[8];
    const float* bih = (const float*)d_in[9];
    const float* bhh = (const float*)d_in[10];
    float* out = (float*)d_out;
    unsigned char* ws = (unsigned char*)d_ws;

    // workspace layout (16B-aligned)
    unsigned short* hc_h  = (unsigned short*)(ws + 0);        // [1024,1024] fp16 = 2 MB
    unsigned short* iWh_h = (unsigned short*)(ws + 2097152);  // [256,1024]
    unsigned short* iWc_h = (unsigned short*)(ws + 2621440);  // [256,1024]
    unsigned short* Wih_h = (unsigned short*)(ws + 3145728);  // [1024,512]
    unsigned short* Whh_h = (unsigned short*)(ws + 4194304);  // [1024,256]
    float* h0 = (float*)(ws + 4718592);                        // [1024,256]
    float* c0 = (float*)(ws + 5767168);                        // [1024,256]
    float* xp = (float*)(ws + 6815744);                        // [1024,1024]

    hipFuncSetAttribute(reinterpret_cast<const void*>(lstm_rec),
                        hipFuncAttributeMaxDynamicSharedMemorySize, LSTM_LDS_BYTES);

    // fp16 conversions (h|c concat into hc, weights)
    convert_strided<<<512, 256, 0, stream>>>(h,   hc_h,        1024, 512, 1024);
    convert_strided<<<512, 256, 0, stream>>>(c,   hc_h + 512,  1024, 512, 1024);
    convert_strided<<<256, 256, 0, stream>>>(iWh, iWh_h,       256, 1024, 1024);
    convert_strided<<<256, 256, 0, stream>>>(iWc, iWc_h,       256, 1024, 1024);
    convert_strided<<<512, 256, 0, stream>>>(Wih, Wih_h,       1024, 512, 512);
    convert_strided<<<256, 256, 0, stream>>>(Whh, Whh_h,       1024, 256, 256);

    // init states + x_proj
    gemm_bt<<<dim3(16, 4),  256, 0, stream>>>(hc_h, iWh_h, h0, ibh, nullptr, 1024, 1024, 256, 1);
    gemm_bt<<<dim3(16, 4),  256, 0, stream>>>(hc_h, iWc_h, c0, ibc, nullptr, 1024, 1024, 256, 1);
    gemm_bt<<<dim3(16, 16), 256, 0, stream>>>(hc_h, Wih_h, xp, bih, bhh,     512, 1024, 1024, 0);

    // recurrence
    lstm_rec<<<64, 1024, LSTM_LDS_BYTES, stream>>>(Whh_h, xp, h0, c0, seqp, out);
}

// Round 3
// 1354.573 us; speedup vs baseline: 1.0255x; 1.0255x over previous
//
#include <hip/hip_runtime.h>
#include <stdint.h>

typedef __attribute__((ext_vector_type(4))) float f32x4;
typedef __attribute__((ext_vector_type(8))) _Float16 f16x8;

static __device__ __forceinline__ unsigned short f2h(float f) {
    union { _Float16 h; unsigned short u; } v;
    v.h = (_Float16)f;                      // v_cvt_f16_f32, RNE
    return v.u;
}
static __device__ __forceinline__ f16x8 as_f16x8(uint4 v) {
    union { uint4 u; f16x8 s; } x; x.u = v; return x.s;
}
static __device__ __forceinline__ float sigmoid_fast(float x) {
    return __builtin_amdgcn_rcpf(1.0f + __builtin_amdgcn_exp2f(-1.4426950408889634f * x));
}
static __device__ __forceinline__ float tanh_fast(float x) {
    return 1.0f - 2.0f * __builtin_amdgcn_rcpf(1.0f + __builtin_amdgcn_exp2f(2.8853900817779268f * x));
}
// barrier that waits only LDS (lgkmcnt(0)), NOT vmcnt — global stores keep retiring async,
// cross-step weight prefetch stays in flight (CK block_sync_lds idiom).
static __device__ __forceinline__ void lds_barrier() {
    __builtin_amdgcn_s_waitcnt(0xc07f);
    __builtin_amdgcn_s_barrier();
}

// ---------- fused fp32 -> fp16 conversion for all 6 tensors (1 dispatch) ----------
// float4-index regions (compile-time): h 131072 | c 131072 | iWh 65536 | iWc 65536 | Wih 131072 | Whh 65536
__global__ __launch_bounds__(256) void convert_all(
    const float* __restrict__ h, const float* __restrict__ c,
    const float* __restrict__ iWh, const float* __restrict__ iWc,
    const float* __restrict__ Wih, const float* __restrict__ Whh,
    unsigned short* __restrict__ hc_h, unsigned short* __restrict__ iWh_h,
    unsigned short* __restrict__ iWc_h, unsigned short* __restrict__ Wih_h,
    unsigned short* __restrict__ Whh_h) {
    int i = blockIdx.x * 256 + threadIdx.x;      // float4 index, total 589824
    const float* src; unsigned short* dst;
    if (i < 131072) {            // h -> hc[:, 0:512]
        int base = i * 4, r = base >> 9, cc = base & 511;
        src = h + base; dst = hc_h + r * 1024 + cc;
    } else if (i < 262144) {     // c -> hc[:, 512:1024]
        int j = i - 131072; int base = j * 4, r = base >> 9, cc = base & 511;
        src = c + base; dst = hc_h + r * 1024 + 512 + cc;
    } else if (i < 327680) { int j = i - 262144; src = iWh + j * 4; dst = iWh_h + j * 4; }
    else if (i < 393216)   { int j = i - 327680; src = iWc + j * 4; dst = iWc_h + j * 4; }
    else if (i < 524288)   { int j = i - 393216; src = Wih + j * 4; dst = Wih_h + j * 4; }
    else                   { int j = i - 524288; src = Whh + j * 4; dst = Whh_h + j * 4; }
    float4 v = *(const float4*)src;
    dst[0] = f2h(v.x); dst[1] = f2h(v.y); dst[2] = f2h(v.z); dst[3] = f2h(v.w);
}

// ---------- generic C[M,N] = A[M,lda] @ W[N,K]^T + bias (+ELU), fp16 in / fp32 out ----------
__global__ __launch_bounds__(256) void gemm_bt(
    const unsigned short* __restrict__ A, const unsigned short* __restrict__ W,
    float* __restrict__ C, const float* __restrict__ b1, const float* __restrict__ b2,
    int K, int lda, int N, int do_elu) {
    __shared__ unsigned short As[64][40];
    __shared__ unsigned short Bs[64][40];
    int tid = threadIdx.x;
    int lane = tid & 63, wv = tid >> 6;
    int q = lane >> 4, l15 = lane & 15;
    int Mbase = blockIdx.x * 64, Nbase = blockIdx.y * 64;
    int ldrow = tid >> 2, seg = tid & 3;
    const unsigned short* Ap = A + (size_t)(Mbase + ldrow) * lda + seg * 8;
    const unsigned short* Wp = W + (size_t)(Nbase + ldrow) * K + seg * 8;
    f32x4 acc[4] = {};
    for (int k0 = 0; k0 < K; k0 += 32) {
        uint4 av = *(const uint4*)(Ap + k0);
        uint4 wvv = *(const uint4*)(Wp + k0);
        __syncthreads();
        *(uint4*)(&As[ldrow][seg * 8]) = av;
        *(uint4*)(&Bs[ldrow][seg * 8]) = wvv;
        __syncthreads();
        f16x8 af = *(const f16x8*)(&As[wv * 16 + l15][q * 8]);
#pragma unroll
        for (int nt = 0; nt < 4; nt++) {
            f16x8 bf = *(const f16x8*)(&Bs[nt * 16 + l15][q * 8]);
            acc[nt] = __builtin_amdgcn_mfma_f32_16x16x32_f16(af, bf, acc[nt], 0, 0, 0);
        }
    }
#pragma unroll
    for (int nt = 0; nt < 4; nt++) {
        int col = Nbase + nt * 16 + l15;
        float bias = b1[col] + (b2 ? b2[col] : 0.0f);
#pragma unroll
        for (int r = 0; r < 4; r++) {
            int row = Mbase + wv * 16 + q * 4 + r;
            float v = acc[nt][r] + bias;
            if (do_elu) v = v > 0.0f ? v : (__builtin_amdgcn_exp2f(1.4426950408889634f * v) - 1.0f);
            C[(size_t)row * N + col] = v;
        }
    }
}

// ---------- fused init-state GEMMs (h0 and c0 via blockIdx.z), K=1024, N=256, ELU ----------
__global__ __launch_bounds__(256) void gemm_init(
    const unsigned short* __restrict__ A,
    const unsigned short* __restrict__ W0, const unsigned short* __restrict__ W1,
    float* __restrict__ C0, float* __restrict__ C1,
    const float* __restrict__ bias0, const float* __restrict__ bias1) {
    const unsigned short* W = blockIdx.z ? W1 : W0;
    float* C = blockIdx.z ? C1 : C0;
    const float* bias = blockIdx.z ? bias1 : bias0;
    __shared__ unsigned short As[64][40];
    __shared__ unsigned short Bs[64][40];
    int tid = threadIdx.x;
    int lane = tid & 63, wv = tid >> 6;
    int q = lane >> 4, l15 = lane & 15;
    int Mbase = blockIdx.x * 64, Nbase = blockIdx.y * 64;
    int ldrow = tid >> 2, seg = tid & 3;
    const unsigned short* Ap = A + (size_t)(Mbase + ldrow) * 1024 + seg * 8;
    const unsigned short* Wp = W + (size_t)(Nbase + ldrow) * 1024 + seg * 8;
    f32x4 acc[4] = {};
    for (int k0 = 0; k0 < 1024; k0 += 32) {
        uint4 av = *(const uint4*)(Ap + k0);
        uint4 wvv = *(const uint4*)(Wp + k0);
        __syncthreads();
        *(uint4*)(&As[ldrow][seg * 8]) = av;
        *(uint4*)(&Bs[ldrow][seg * 8]) = wvv;
        __syncthreads();
        f16x8 af = *(const f16x8*)(&As[wv * 16 + l15][q * 8]);
#pragma unroll
        for (int nt = 0; nt < 4; nt++) {
            f16x8 bf = *(const f16x8*)(&Bs[nt * 16 + l15][q * 8]);
            acc[nt] = __builtin_amdgcn_mfma_f32_16x16x32_f16(af, bf, acc[nt], 0, 0, 0);
        }
    }
#pragma unroll
    for (int nt = 0; nt < 4; nt++) {
        int col = Nbase + nt * 16 + l15;
        float b = bias[col];
#pragma unroll
        for (int r = 0; r < 4; r++) {
            int row = Mbase + wv * 16 + q * 4 + r;
            float v = acc[nt][r] + b;
            v = v > 0.0f ? v : (__builtin_amdgcn_exp2f(1.4426950408889634f * v) - 1.0f);
            C[(size_t)row * 256 + col] = v;
        }
    }
}

// ---------- persistent recurrent kernel: 64 blocks x 1024 thr, 16 rows/block ----------
// wave w owns latent cols [16w,16w+16) for all 4 gates (i,f,g,o in-register elementwise).
// W_hh frags: kt0-1 in VGPRs, kt2-3 in LDS, kt4-7 streamed from L2 each step (prefetched).
// __launch_bounds__(1024, 4): 4 waves/EU => 1 block/CU => 128-VGPR budget (round-2 ran at
// 64 VGPRs and spilled the whole weight set to scratch every step -> 1130 us).
#define HB_STRIDE 264                    // fp16 elems per h row (padded)
#define HB_HALF   (16 * HB_STRIDE)      // one h buffer, elems
#define WLDS_OFF  (2 * HB_HALF * 2)     // bytes: 16896
#define LSTM_LDS_BYTES (WLDS_OFF + 16 * 8 * 64 * 16)   // 147968

__global__ __launch_bounds__(1024, 4) void lstm_rec(
    const unsigned short* __restrict__ Whh,   // [1024,256] fp16
    const float* __restrict__ xp,             // [1024,1024]
    const float* __restrict__ h0,             // [1024,256]
    const float* __restrict__ c0,             // [1024,256]
    const int* __restrict__ seq_len,
    float* __restrict__ out)                  // [1024, T, 256]
{
    extern __shared__ unsigned char smem[];
    unsigned short* hbuf = (unsigned short*)smem;        // [2][16][HB_STRIDE]
    unsigned char* wlds = smem + WLDS_OFF;               // 16 waves * 8 frags * 64 lanes * 16B
    int tid = threadIdx.x;
    int lane = tid & 63, wv = tid >> 6;
    int q = lane >> 4, l15 = lane & 15;
    int T = *seq_len;
    int rowbase = blockIdx.x * 16;

    // global base for this wave's weight fragments: row = g*256 + wv*16 + l15, k = kt*32 + q*8
    const unsigned short* wbase = Whh + ((wv << 4) + l15) * 256 + q * 8;

    uint4 wreg[8];
#pragma unroll
    for (int kt = 0; kt < 2; kt++)
#pragma unroll
        for (int g = 0; g < 4; g++)
            wreg[kt * 4 + g] = *(const uint4*)(wbase + (size_t)g * 65536 + kt * 32);
#pragma unroll
    for (int kt = 2; kt < 4; kt++)
#pragma unroll
        for (int g = 0; g < 4; g++) {
            uint4 v = *(const uint4*)(wbase + (size_t)g * 65536 + kt * 32);
            *(uint4*)(wlds + ((size_t)((wv * 8) + (kt - 2) * 4 + g) * 64 + lane) * 16) = v;
        }

    float xpr[16];
#pragma unroll
    for (int g = 0; g < 4; g++)
#pragma unroll
        for (int r = 0; r < 4; r++)
            xpr[g * 4 + r] = xp[(size_t)(rowbase + q * 4 + r) * 1024 + g * 256 + wv * 16 + l15];

    float creg[4];
#pragma unroll
    for (int r = 0; r < 4; r++)
        creg[r] = c0[(size_t)(rowbase + q * 4 + r) * 256 + wv * 16 + l15];

    {   // h0 -> hbuf[0] as fp16
        int e = tid * 4;
        int r = e >> 8, cc = e & 255;
        float4 v = *(const float4*)(h0 + (size_t)(rowbase + r) * 256 + cc);
        unsigned short* d = hbuf + r * HB_STRIDE + cc;
        d[0] = f2h(v.x); d[1] = f2h(v.y); d[2] = f2h(v.z); d[3] = f2h(v.w);
    }
    __syncthreads();

    // prefetch streamed kt4 (weight addresses are step-invariant)
    uint4 sbuf[4];
#pragma unroll
    for (int g = 0; g < 4; g++) sbuf[g] = *(const uint4*)(wbase + (size_t)g * 65536 + 4 * 32);

    for (int t = 0; t < T; t++) {
        unsigned short* hc = hbuf + (t & 1) * HB_HALF;
        f32x4 acc[4];
#pragma unroll
        for (int g = 0; g < 4; g++) {
            acc[g][0] = xpr[g * 4 + 0]; acc[g][1] = xpr[g * 4 + 1];
            acc[g][2] = xpr[g * 4 + 2]; acc[g][3] = xpr[g * 4 + 3];
        }
        // kt 0..1: register-resident weights
#pragma unroll
        for (int kt = 0; kt < 2; kt++) {
            f16x8 af = *(const f16x8*)(hc + l15 * HB_STRIDE + kt * 32 + q * 8);
#pragma unroll
            for (int g = 0; g < 4; g++)
                acc[g] = __builtin_amdgcn_mfma_f32_16x16x32_f16(af, as_f16x8(wreg[kt * 4 + g]), acc[g], 0, 0, 0);
        }
        // kt 2..3: LDS-resident weights
#pragma unroll
        for (int kt = 2; kt < 4; kt++) {
            f16x8 af = *(const f16x8*)(hc + l15 * HB_STRIDE + kt * 32 + q * 8);
#pragma unroll
            for (int g = 0; g < 4; g++) {
                f16x8 bf = *(const f16x8*)(wlds + ((size_t)((wv * 8) + (kt - 2) * 4 + g) * 64 + lane) * 16);
                acc[g] = __builtin_amdgcn_mfma_f32_16x16x32_f16(af, bf, acc[g], 0, 0, 0);
            }
        }
        // kt 4..7: streamed from L2; consume sbuf[g] then refill in place (kt7 refills next
        // step's kt4 — the lds_barrier below does NOT drain vmcnt, so it stays in flight)
#pragma unroll
        for (int kt = 4; kt < 8; kt++) {
            f16x8 af = *(const f16x8*)(hc + l15 * HB_STRIDE + kt * 32 + q * 8);
            int nkt = (kt < 7) ? (kt + 1) : 4;
#pragma unroll
            for (int g = 0; g < 4; g++) {
                acc[g] = __builtin_amdgcn_mfma_f32_16x16x32_f16(af, as_f16x8(sbuf[g]), acc[g], 0, 0, 0);
                sbuf[g] = *(const uint4*)(wbase + (size_t)g * 65536 + nkt * 32);
            }
        }
        // elementwise (in-register), write ys and next h
        unsigned short* hn = hbuf + ((t + 1) & 1) * HB_HALF;
#pragma unroll
        for (int r = 0; r < 4; r++) {
            float ig = sigmoid_fast(acc[0][r]);
            float fg = sigmoid_fast(acc[1][r]);
            float gg = tanh_fast(acc[2][r]);
            float og = sigmoid_fast(acc[3][r]);
            float cn = fg * creg[r] + ig * gg;
            creg[r] = cn;
            float hv = og * tanh_fast(cn);
            out[((size_t)(rowbase + q * 4 + r) * T + t) * 256 + wv * 16 + l15] = hv;
            hn[(q * 4 + r) * HB_STRIDE + wv * 16 + l15] = f2h(hv);
        }
        lds_barrier();
    }
}

extern "C" void kernel_launch(void* const* d_in, const int* in_sizes, int n_in,
                              void* d_out, int out_size, void* d_ws, size_t ws_size,
                              hipStream_t stream) {
    const float* h   = (const float*)d_in[0];
    const float* c   = (const float*)d_in[1];
    const int*   seqp= (const int*)d_in[2];
    const float* iWh = (const float*)d_in[3];
    const float* ibh = (const float*)d_in[4];
    const float* iWc = (const float*)d_in[5];
    const float* ibc = (const float*)d_in[6];
    const float* Wih = (const float*)d_in[7];
    const float* Whh = (const float*)d_in[8];
    const float* bih = (const float*)d_in[9];
    const float* bhh = (const float*)d_in[10];
    float* out = (float*)d_out;
    unsigned char* ws = (unsigned char*)d_ws;

    // workspace layout (16B-aligned)
    unsigned short* hc_h  = (unsigned short*)(ws + 0);        // [1024,1024] fp16 = 2 MB
    unsigned short* iWh_h = (unsigned short*)(ws + 2097152);  // [256,1024]
    unsigned short* iWc_h = (unsigned short*)(ws + 2621440);  // [256,1024]
    unsigned short* Wih_h = (unsigned short*)(ws + 3145728);  // [1024,512]
    unsigned short* Whh_h = (unsigned short*)(ws + 4194304);  // [1024,256]
    float* h0 = (float*)(ws + 4718592);                        // [1024,256]
    float* c0 = (float*)(ws + 5767168);                        // [1024,256]
    float* xp = (float*)(ws + 6815744);                        // [1024,1024]

    hipFuncSetAttribute(reinterpret_cast<const void*>(lstm_rec),
                        hipFuncAttributeMaxDynamicSharedMemorySize, LSTM_LDS_BYTES);

    // fp16 conversions: all 6 tensors in one dispatch
    convert_all<<<2304, 256, 0, stream>>>(h, c, iWh, iWc, Wih, Whh,
                                          hc_h, iWh_h, iWc_h, Wih_h, Whh_h);

    // init states (fused pair) + x_proj
    gemm_init<<<dim3(16, 4, 2), 256, 0, stream>>>(hc_h, iWh_h, iWc_h, h0, c0, ibh, ibc);
    gemm_bt<<<dim3(16, 16), 256, 0, stream>>>(hc_h, Wih_h, xp, bih, bhh, 512, 1024, 1024, 0);

    // recurrence
    lstm_rec<<<64, 1024, LSTM_LDS_BYTES, stream>>>(Whh_h, xp, h0, c0, seqp, out);
}